// Round 1
// baseline (262.062 us; speedup 1.0000x reference)
//
#include <hip/hip_runtime.h>
#include <hip/hip_bf16.h>
#include <math.h>

// KNRM fused kernel for MI355X (gfx950) — round 9.
// B=256, Q=32, D=512, E=300, V=100k, K=11.
//
// R9 = R8 (producer/consumer wave specialization, double-buffered doc tiles)
// + depth-2 producer pipeline: loads for chunk ch+2 are ISSUED in iteration
// ch (one barrier-window before their convert+write in iteration ch+1), so
// gather latency hides under a full chunk of consumer compute + BW drain.
// Loads and uses sit in different BBs separated by __syncthreads, so the
// per-BB machine scheduler cannot re-sink them (R2/R3/R6/R7 failure mode).
// + consumer q-fragments (av) and qscale hoisted to registers: removes
// 10 ds_read_b128 + lgkm waits per chunk per consumer wave.
// Kernel 0 (sigma=1e-4) = exact-token-match counter via integer compare.

#define NB 256
#define NQ 32
#define ND 512
#define NE 300
#define LROW 328    // LDS row stride in bf16 (656 B = 16B-aligned, 4-bank row skew)
#define SPLITS 2
#define DPB 256     // docs per block
#define CHUNK 32
#define NCHUNK 8
#define NT 512
#define NK 11
#define QK_SZ (NQ * NK)   // 352

typedef __bf16 bf16x8 __attribute__((ext_vector_type(8)));
typedef __bf16 bf16x4 __attribute__((ext_vector_type(4)));
typedef float f32x4 __attribute__((ext_vector_type(4)));

__global__ __launch_bounds__(NT, 4) void knrm_main(
    const int* __restrict__ qtok,
    const int* __restrict__ dtok,
    const float* __restrict__ emb,
    float* __restrict__ partial)   // [NB][SPLITS][QK_SZ]
{
  __shared__ __align__(16) __bf16 qlds[NQ][LROW];          // 20992 B
  __shared__ __align__(16) __bf16 dlds[2][CHUNK][LROW];    // 41984 B
  __shared__ float qscale[NQ];
  __shared__ float dscale[2][CHUNK];
  __shared__ float qkl[QK_SZ];

  const int b    = blockIdx.x >> 1;
  const int sp   = blockIdx.x & 1;
  const int t    = threadIdx.x;
  const int lane = t & 63;
  const int w    = t >> 6;
  const bool producer = (w < 4);   // waves 0-3 stage docs; waves 4-7 compute

  // ---- producer-persistent pipeline state (consumer path never touches) ----
  float4 v[10];                    // in-flight doc row (issued 1 window early)
  int td_w = 0;                    // token of the chunk v currently holds
  const int dr = t >> 3;           // producer doc row 0..31 (threads 0..255)
  const int dj = t & 7;
  const int tokbase = b * ND + sp * DPB;

  auto issue_loads = [&](int td) {
    const float4* rowp = (const float4*)(emb + (size_t)td * NE);
    #pragma unroll
    for (int i = 0; i < 9; ++i) v[i] = rowp[dj + 8 * i];
    v[9] = (dj < 3) ? rowp[dj + 72] : make_float4(0.f, 0.f, 0.f, 0.f);
    __builtin_amdgcn_sched_barrier(0);   // pin issue cluster before barrier
  };

  auto convert_write = [&](int buf, int td) {
    float ss = 0.0f;
    #pragma unroll
    for (int i = 0; i < 10; ++i) {
      ss += v[i].x * v[i].x + v[i].y * v[i].y + v[i].z * v[i].z + v[i].w * v[i].w;
      if (i < 9 || dj < 3) {
        bf16x4 h;
        h[0] = (__bf16)v[i].x; h[1] = (__bf16)v[i].y;
        h[2] = (__bf16)v[i].z; h[3] = (__bf16)v[i].w;
        *(bf16x4*)&dlds[buf][dr][4 * (dj + 8 * i)] = h;
      }
    }
    if (dj < 5) { bf16x4 z = {}; *(bf16x4*)&dlds[buf][dr][NE + 4 * dj] = z; }  // K-pad
    ss += __shfl_xor(ss, 1, 8);
    ss += __shfl_xor(ss, 2, 8);
    ss += __shfl_xor(ss, 4, 8);
    if (dj == 0) dscale[buf][dr] = (td > 0) ? 1.0f / (sqrtf(ss) + 1e-13f) : 0.0f;
  };

  // ---- phase A: producers stage chunk 0 + issue chunk 1; consumers do query ----
  if (producer) {
    for (int i = t; i < QK_SZ; i += 256)      // zero qkl for k>=1
      if (i % NK) qkl[i] = 0.0f;
    td_w = dtok[tokbase + dr];
    issue_loads(td_w);
    convert_write(0, td_w);                    // chunk 0 -> dlds[0]
    td_w = dtok[tokbase + CHUNK + dr];
    issue_loads(td_w);                         // chunk 1 in flight across barrier
  } else {
    const int r = (t >> 3) & 31;   // query row 0..31 (8 threads per row)
    const int j = t & 7;
    const int tq = qtok[b * NQ + r];
    const float4* rowp = (const float4*)(emb + (size_t)tq * NE);

    float4 qv[10];
    #pragma unroll
    for (int i = 0; i < 9; ++i) qv[i] = rowp[j + 8 * i];
    qv[9] = (j < 3) ? rowp[j + 72] : make_float4(0.f, 0.f, 0.f, 0.f);

    float ss = 0.0f;
    #pragma unroll
    for (int i = 0; i < 10; ++i) {
      ss += qv[i].x * qv[i].x + qv[i].y * qv[i].y + qv[i].z * qv[i].z + qv[i].w * qv[i].w;
      if (i < 9 || j < 3) {
        bf16x4 h;
        h[0] = (__bf16)qv[i].x; h[1] = (__bf16)qv[i].y;
        h[2] = (__bf16)qv[i].z; h[3] = (__bf16)qv[i].w;
        *(bf16x4*)&qlds[r][4 * (j + 8 * i)] = h;
      }
    }
    if (j < 5) { bf16x4 z = {}; *(bf16x4*)&qlds[r][NE + 4 * j] = z; }  // K-pad
    ss += __shfl_xor(ss, 1, 8);
    ss += __shfl_xor(ss, 2, 8);
    ss += __shfl_xor(ss, 4, 8);
    if (j == 0) qscale[r] = (tq > 0) ? 1.0f / (sqrtf(ss) + 1e-13f) : 0.0f;

    // kernel 0: count of this block's DPB docs with identical (nonzero) token
    int cnt = 0;
    #pragma unroll 4
    for (int jj = 0; jj < 32; ++jj) {
      int td = dtok[b * ND + sp * DPB + j + 8 * jj];
      cnt += (tq > 0 && td == tq) ? 1 : 0;
    }
    cnt += __shfl_xor(cnt, 1, 8);
    cnt += __shfl_xor(cnt, 2, 8);
    cnt += __shfl_xor(cnt, 4, 8);
    if (j == 0) qkl[r * NK] = (float)cnt;
  }
  __syncthreads();   // qlds/qscale/qkl + chunk 0 ready; chunk 1 loads in flight

  // ---- consumer tile assignment: 4 waves cover 2 m-tiles x 2 n-tiles ----
  const int cw   = w - 4;          // consumer wave 0..3
  const int mt   = cw >> 1;        // q rows 16mt..16mt+15
  const int nt   = cw & 1;         // docs 16nt..16nt+15 within chunk
  const int l15  = lane & 15;
  const int quad = lane >> 4;

  const float muk[10] = {0.9f, 0.7f, 0.5f, 0.3f, 0.1f,
                         -0.1f, -0.3f, -0.5f, -0.7f, -0.9f};
  float rbfacc[4][10];
  bf16x8 av[10];
  float qsr[4];
  if (!producer) {
    // hoist q fragments + q scales into registers (qlds is dead after this)
    const __bf16* ap = &qlds[mt * 16 + l15][quad * 8];
    #pragma unroll
    for (int kk = 0; kk < 10; ++kk) av[kk] = *(const bf16x8*)(ap + kk * 32);
    #pragma unroll
    for (int r4 = 0; r4 < 4; ++r4) {
      qsr[r4] = qscale[mt * 16 + quad * 4 + r4];
      #pragma unroll
      for (int k = 0; k < 10; ++k) rbfacc[r4][k] = 0.0f;
    }
  }

  // ---- main loop: producers write ch+1 (preloaded) + issue ch+2; consumers ch ----
  #pragma unroll 1
  for (int ch = 0; ch < NCHUNK; ++ch) {
    if (producer) {
      if (ch + 1 < NCHUNK) {
        convert_write((ch + 1) & 1, td_w);   // data issued one window ago
        if (ch + 2 < NCHUNK) {
          int td_i = dtok[tokbase + (ch + 2) * CHUNK + dr];
          issue_loads(td_i);                 // stays in flight across barrier
          td_w = td_i;
        }
      }
    } else {
      const int buf = ch & 1;
      const __bf16* bptr = &dlds[buf][nt * 16 + l15][quad * 8];

      f32x4 acc = {};
      #pragma unroll
      for (int kk = 0; kk < 10; ++kk) {
        bf16x8 bv = *(const bf16x8*)(bptr + kk * 32);
        acc = __builtin_amdgcn_mfma_f32_16x16x32_bf16(av[kk], bv, acc, 0, 0, 0);
      }

      // RBF accumulate (kernels 1..10). C layout: col(doc)=l15, row(q)=quad*4+reg.
      const float ds = dscale[buf][nt * 16 + l15];
      #pragma unroll
      for (int r4 = 0; r4 < 4; ++r4) {
        const float s = qsr[r4] * ds;
        const float mm = (s == 0.0f) ? 1e8f : acc[r4] * s;  // masked -> rbf underflows to 0
        #pragma unroll
        for (int k = 0; k < 10; ++k) {
          float d = mm - muk[k];
          rbfacc[r4][k] += __builtin_amdgcn_exp2f(d * d * -72.13475204444817f);
        }
      }
    }
    __syncthreads();   // chunk ch+1 written; consumers done reading buf ch&1
  }

  // ---- consumers: reduce rbfacc over the 16 doc-columns, add into qkl ----
  if (!producer) {
    #pragma unroll
    for (int r4 = 0; r4 < 4; ++r4)
      #pragma unroll
      for (int k = 0; k < 10; ++k) {
        float vv = rbfacc[r4][k];
        vv += __shfl_xor(vv, 1);
        vv += __shfl_xor(vv, 2);
        vv += __shfl_xor(vv, 4);
        vv += __shfl_xor(vv, 8);
        if (l15 == 0) atomicAdd(&qkl[(mt * 16 + quad * 4 + r4) * NK + k + 1], vv);
      }
  }
  __syncthreads();

  // ---- write this block's partial qk slice ----
  float* pp = partial + ((size_t)b * SPLITS + sp) * QK_SZ;
  for (int i = t; i < QK_SZ; i += NT) pp[i] = qkl[i];
}

__global__ __launch_bounds__(64) void knrm_epi(
    const float* __restrict__ partial,
    const float* __restrict__ fcw,
    const float* __restrict__ fcb,
    float* __restrict__ out)
{
  const int b = blockIdx.x;
  const int lane = threadIdx.x;
  const float* pb = partial + (size_t)b * SPLITS * QK_SZ;
  float acc = 0.0f;
  for (int i = lane; i < QK_SZ; i += 64) {
    float s = pb[i] + pb[i + QK_SZ];
    acc += logf(fmaxf(s, 1e-10f)) * 0.01f * fcw[i % NK];
  }
  #pragma unroll
  for (int off = 1; off < 64; off <<= 1) acc += __shfl_xor(acc, off);
  if (lane == 0) out[b] = acc + fcb[0];
}

extern "C" void kernel_launch(void* const* d_in, const int* in_sizes, int n_in,
                              void* d_out, int out_size, void* d_ws, size_t ws_size,
                              hipStream_t stream) {
  const int* qtok = (const int*)d_in[0];
  const int* dtok = (const int*)d_in[1];
  const float* emb = (const float*)d_in[2];
  const float* fcw = (const float*)d_in[3];
  const float* fcb = (const float*)d_in[4];
  float* out = (float*)d_out;
  float* partial = (float*)d_ws;   // NB*SPLITS*QK_SZ floats = 720 KB

  knrm_main<<<NB * SPLITS, NT, 0, stream>>>(qtok, dtok, emb, partial);
  knrm_epi<<<NB, 64, 0, stream>>>(partial, fcw, fcb, out);
}

// Round 2
// 210.886 us; speedup vs baseline: 1.2427x; 1.2427x over previous
//
#include <hip/hip_runtime.h>
#include <hip/hip_bf16.h>
#include <math.h>

// KNRM fused kernel for MI355X (gfx950) — round 10.
// B=256, Q=32, D=512, E=300, V=100k, K=11.
//
// R10 = R8 (best known: producer/consumer wave specialization, double-buffered
// doc tiles, separate epi kernel) + depth-2 producer pipeline done RIGHT:
//  - main-loop barriers are raw s_barrier with an lgkmcnt(0)-only wait
//    (HK/T4 pattern). __syncthreads() would emit s_waitcnt vmcnt(0) and drain
//    the in-flight chunk-(ch+2) gather loads at every barrier (R9's regression
//    mechanism #1). vmcnt is NEVER drained in the main loop; the convert of
//    chunk ch+1 auto-waits only on its own (window-old, already-landed) loads.
//  - R9's av[10] consumer hoist reverted: it pushed the consumer live set past
//    the allocator budget -> scratch spills (R9: WRITE_SIZE 160 MB of scratch
//    traffic). Consumers read q-fragments from LDS per chunk, as in R8.
// Kernel 0 (sigma=1e-4) = exact-token-match counter via integer compare.

#define NB 256
#define NQ 32
#define ND 512
#define NE 300
#define LROW 328    // LDS row stride in bf16 (656 B = 16B-aligned, 4-bank row skew)
#define SPLITS 2
#define DPB 256     // docs per block
#define CHUNK 32
#define NCHUNK 8
#define NT 512
#define NK 11
#define QK_SZ (NQ * NK)   // 352

typedef __bf16 bf16x8 __attribute__((ext_vector_type(8)));
typedef __bf16 bf16x4 __attribute__((ext_vector_type(4)));
typedef float f32x4 __attribute__((ext_vector_type(4)));

// lgkmcnt(0)-only barrier: producer ds_writes drained, global loads stay in flight.
__device__ __forceinline__ void lds_barrier() {
  asm volatile("s_waitcnt lgkmcnt(0)" ::: "memory");
  __builtin_amdgcn_s_barrier();
  __builtin_amdgcn_sched_barrier(0);
}

__global__ __launch_bounds__(NT, 4) void knrm_main(
    const int* __restrict__ qtok,
    const int* __restrict__ dtok,
    const float* __restrict__ emb,
    float* __restrict__ partial)   // [NB][SPLITS][QK_SZ]
{
  __shared__ __align__(16) __bf16 qlds[NQ][LROW];          // 20992 B
  __shared__ __align__(16) __bf16 dlds[2][CHUNK][LROW];    // 41984 B
  __shared__ float qscale[NQ];
  __shared__ float dscale[2][CHUNK];
  __shared__ float qkl[QK_SZ];

  const int b    = blockIdx.x >> 1;
  const int sp   = blockIdx.x & 1;
  const int t    = threadIdx.x;
  const int lane = t & 63;
  const int w    = t >> 6;
  const bool producer = (w < 4);   // waves 0-3 stage docs; waves 4-7 compute

  // ---- producer-persistent pipeline state (consumer path never touches) ----
  float4 v[10];                    // in-flight doc row (issued 1 window early)
  int td_w = 0;                    // token of the chunk v currently holds
  const int dr = t >> 3;           // producer doc row 0..31 (threads 0..255)
  const int dj = t & 7;
  const int tokbase = b * ND + sp * DPB;

  auto issue_loads = [&](int td) {
    const float4* rowp = (const float4*)(emb + (size_t)td * NE);
    #pragma unroll
    for (int i = 0; i < 9; ++i) v[i] = rowp[dj + 8 * i];
    v[9] = (dj < 3) ? rowp[dj + 72] : make_float4(0.f, 0.f, 0.f, 0.f);
    __builtin_amdgcn_sched_barrier(0);   // pin issue cluster here
  };

  auto convert_write = [&](int buf, int td) {
    float ss = 0.0f;
    #pragma unroll
    for (int i = 0; i < 10; ++i) {
      ss += v[i].x * v[i].x + v[i].y * v[i].y + v[i].z * v[i].z + v[i].w * v[i].w;
      if (i < 9 || dj < 3) {
        bf16x4 h;
        h[0] = (__bf16)v[i].x; h[1] = (__bf16)v[i].y;
        h[2] = (__bf16)v[i].z; h[3] = (__bf16)v[i].w;
        *(bf16x4*)&dlds[buf][dr][4 * (dj + 8 * i)] = h;
      }
    }
    if (dj < 5) { bf16x4 z = {}; *(bf16x4*)&dlds[buf][dr][NE + 4 * dj] = z; }  // K-pad
    ss += __shfl_xor(ss, 1, 8);
    ss += __shfl_xor(ss, 2, 8);
    ss += __shfl_xor(ss, 4, 8);
    if (dj == 0) dscale[buf][dr] = (td > 0) ? 1.0f / (sqrtf(ss) + 1e-13f) : 0.0f;
  };

  // ---- phase A: producers stage chunk 0 + issue chunk 1; consumers do query ----
  if (producer) {
    for (int i = t; i < QK_SZ; i += 256)      // zero qkl for k>=1
      if (i % NK) qkl[i] = 0.0f;
    td_w = dtok[tokbase + dr];
    issue_loads(td_w);
    convert_write(0, td_w);                    // chunk 0 -> dlds[0]
    td_w = dtok[tokbase + CHUNK + dr];
    issue_loads(td_w);                         // chunk 1 in flight across barrier
  } else {
    const int r = (t >> 3) & 31;   // query row 0..31 (8 threads per row)
    const int j = t & 7;
    const int tq = qtok[b * NQ + r];
    const float4* rowp = (const float4*)(emb + (size_t)tq * NE);

    float4 qv[10];
    #pragma unroll
    for (int i = 0; i < 9; ++i) qv[i] = rowp[j + 8 * i];
    qv[9] = (j < 3) ? rowp[j + 72] : make_float4(0.f, 0.f, 0.f, 0.f);

    float ss = 0.0f;
    #pragma unroll
    for (int i = 0; i < 10; ++i) {
      ss += qv[i].x * qv[i].x + qv[i].y * qv[i].y + qv[i].z * qv[i].z + qv[i].w * qv[i].w;
      if (i < 9 || j < 3) {
        bf16x4 h;
        h[0] = (__bf16)qv[i].x; h[1] = (__bf16)qv[i].y;
        h[2] = (__bf16)qv[i].z; h[3] = (__bf16)qv[i].w;
        *(bf16x4*)&qlds[r][4 * (j + 8 * i)] = h;
      }
    }
    if (j < 5) { bf16x4 z = {}; *(bf16x4*)&qlds[r][NE + 4 * j] = z; }  // K-pad
    ss += __shfl_xor(ss, 1, 8);
    ss += __shfl_xor(ss, 2, 8);
    ss += __shfl_xor(ss, 4, 8);
    if (j == 0) qscale[r] = (tq > 0) ? 1.0f / (sqrtf(ss) + 1e-13f) : 0.0f;

    // kernel 0: count of this block's DPB docs with identical (nonzero) token
    int cnt = 0;
    #pragma unroll 4
    for (int jj = 0; jj < 32; ++jj) {
      int td = dtok[b * ND + sp * DPB + j + 8 * jj];
      cnt += (tq > 0 && td == tq) ? 1 : 0;
    }
    cnt += __shfl_xor(cnt, 1, 8);
    cnt += __shfl_xor(cnt, 2, 8);
    cnt += __shfl_xor(cnt, 4, 8);
    if (j == 0) qkl[r * NK] = (float)cnt;
  }
  lds_barrier();   // qlds/qscale/qkl + chunk 0 ready; chunk-1 loads stay in flight

  // ---- consumer tile assignment: 4 waves cover 2 m-tiles x 2 n-tiles ----
  const int cw   = w - 4;          // consumer wave 0..3
  const int mt   = cw >> 1;        // q rows 16mt..16mt+15
  const int nt   = cw & 1;         // docs 16nt..16nt+15 within chunk
  const int l15  = lane & 15;
  const int quad = lane >> 4;

  const float muk[10] = {0.9f, 0.7f, 0.5f, 0.3f, 0.1f,
                         -0.1f, -0.3f, -0.5f, -0.7f, -0.9f};
  float rbfacc[4][10];
  #pragma unroll
  for (int r4 = 0; r4 < 4; ++r4)
    #pragma unroll
    for (int k = 0; k < 10; ++k) rbfacc[r4][k] = 0.0f;

  const __bf16* aptr = &qlds[((mt < 0 ? 0 : mt) * 16 + l15) & 31][quad * 8];

  // ---- main loop: producers convert ch+1 (window-old loads) + issue ch+2 ----
  #pragma unroll 1
  for (int ch = 0; ch < NCHUNK; ++ch) {
    if (producer) {
      if (ch + 1 < NCHUNK) {
        convert_write((ch + 1) & 1, td_w);   // waits only its own vm loads
        if (ch + 2 < NCHUNK) {
          int td_i = dtok[tokbase + (ch + 2) * CHUNK + dr];
          issue_loads(td_i);                 // stays in flight across barrier
          td_w = td_i;
        }
      }
    } else {
      const int buf = ch & 1;
      const __bf16* bptr = &dlds[buf][nt * 16 + l15][quad * 8];

      f32x4 acc = {};
      #pragma unroll
      for (int kk = 0; kk < 10; ++kk) {
        bf16x8 av = *(const bf16x8*)(aptr + kk * 32);
        bf16x8 bv = *(const bf16x8*)(bptr + kk * 32);
        acc = __builtin_amdgcn_mfma_f32_16x16x32_bf16(av, bv, acc, 0, 0, 0);
      }

      // RBF accumulate (kernels 1..10). C layout: col(doc)=l15, row(q)=quad*4+reg.
      const float ds = dscale[buf][nt * 16 + l15];
      #pragma unroll
      for (int r4 = 0; r4 < 4; ++r4) {
        const float qs = qscale[mt * 16 + quad * 4 + r4];
        const float s = qs * ds;
        const float mm = (s == 0.0f) ? 1e8f : acc[r4] * s;  // masked -> rbf underflows to 0
        #pragma unroll
        for (int k = 0; k < 10; ++k) {
          float d = mm - muk[k];
          rbfacc[r4][k] += __builtin_amdgcn_exp2f(d * d * -72.13475204444817f);
        }
      }
    }
    lds_barrier();   // chunk ch+1 written; consumers done reading buf ch&1
  }

  // ---- consumers: reduce rbfacc over the 16 doc-columns, add into qkl ----
  if (!producer) {
    #pragma unroll
    for (int r4 = 0; r4 < 4; ++r4)
      #pragma unroll
      for (int k = 0; k < 10; ++k) {
        float vv = rbfacc[r4][k];
        vv += __shfl_xor(vv, 1);
        vv += __shfl_xor(vv, 2);
        vv += __shfl_xor(vv, 4);
        vv += __shfl_xor(vv, 8);
        if (l15 == 0) atomicAdd(&qkl[(mt * 16 + quad * 4 + r4) * NK + k + 1], vv);
      }
  }
  __syncthreads();

  // ---- write this block's partial qk slice ----
  float* pp = partial + ((size_t)b * SPLITS + sp) * QK_SZ;
  for (int i = t; i < QK_SZ; i += NT) pp[i] = qkl[i];
}

__global__ __launch_bounds__(64) void knrm_epi(
    const float* __restrict__ partial,
    const float* __restrict__ fcw,
    const float* __restrict__ fcb,
    float* __restrict__ out)
{
  const int b = blockIdx.x;
  const int lane = threadIdx.x;
  const float* pb = partial + (size_t)b * SPLITS * QK_SZ;
  float acc = 0.0f;
  for (int i = lane; i < QK_SZ; i += 64) {
    float s = pb[i] + pb[i + QK_SZ];
    acc += logf(fmaxf(s, 1e-10f)) * 0.01f * fcw[i % NK];
  }
  #pragma unroll
  for (int off = 1; off < 64; off <<= 1) acc += __shfl_xor(acc, off);
  if (lane == 0) out[b] = acc + fcb[0];
}

extern "C" void kernel_launch(void* const* d_in, const int* in_sizes, int n_in,
                              void* d_out, int out_size, void* d_ws, size_t ws_size,
                              hipStream_t stream) {
  const int* qtok = (const int*)d_in[0];
  const int* dtok = (const int*)d_in[1];
  const float* emb = (const float*)d_in[2];
  const float* fcw = (const float*)d_in[3];
  const float* fcb = (const float*)d_in[4];
  float* out = (float*)d_out;
  float* partial = (float*)d_ws;   // NB*SPLITS*QK_SZ floats = 720 KB

  knrm_main<<<NB * SPLITS, NT, 0, stream>>>(qtok, dtok, emb, partial);
  knrm_epi<<<NB, 64, 0, stream>>>(partial, fcw, fcb, out);
}

// Round 3
// 191.900 us; speedup vs baseline: 1.3656x; 1.0989x over previous
//
#include <hip/hip_runtime.h>
#include <hip/hip_bf16.h>
#include <math.h>

// KNRM fused kernel for MI355X (gfx950) — round 11.
// B=256, Q=32, D=512, E=300, V=100k, K=11.
//
// R11 = R8 (best known, 194.7 us: producer/consumer wave specialization,
// double-buffered doc tiles, __syncthreads barriers, stage-local v[10])
// + two zero-register-cost latency fixes:
//  1. dtok prefetch: all 8 chunk-token rows (1 KB) are loaded ONCE in phase A
//     into tdlds[8][32] (LDS, avoids rule-#20 scratch for runtime-indexed
//     register arrays). R8 paid a cold ~900cy dtok load at the top of EVERY
//     producer window, delaying the payload row-gathers that set the HBM
//     duty cycle (fills flush L2/L3 each iteration, so dtok is always cold).
//  2. K-pad zeroing of dlds rows hoisted to phase A (written once per buffer,
//     never overwritten by stage()).
// R9/R10 post-mortem: persistent cross-barrier register pipelines lose to the
// allocator (spill / codegen overhead) — reverted; barriers stay __syncthreads.
// Kernel 0 (sigma=1e-4) = exact-token-match counter via integer compare.

#define NB 256
#define NQ 32
#define ND 512
#define NE 300
#define LROW 328    // LDS row stride in bf16 (656 B = 16B-aligned, 4-bank row skew)
#define SPLITS 2
#define DPB 256     // docs per block
#define CHUNK 32
#define NCHUNK 8
#define NT 512
#define NK 11
#define QK_SZ (NQ * NK)   // 352

typedef __bf16 bf16x8 __attribute__((ext_vector_type(8)));
typedef __bf16 bf16x4 __attribute__((ext_vector_type(4)));
typedef float f32x4 __attribute__((ext_vector_type(4)));

__global__ __launch_bounds__(NT, 4) void knrm_main(
    const int* __restrict__ qtok,
    const int* __restrict__ dtok,
    const float* __restrict__ emb,
    float* __restrict__ partial)   // [NB][SPLITS][QK_SZ]
{
  __shared__ __align__(16) __bf16 qlds[NQ][LROW];          // 20992 B
  __shared__ __align__(16) __bf16 dlds[2][CHUNK][LROW];    // 41984 B
  __shared__ float qscale[NQ];
  __shared__ float dscale[2][CHUNK];
  __shared__ float qkl[QK_SZ];
  __shared__ int tdlds[NCHUNK][CHUNK];                     // 1024 B token prefetch

  const int b    = blockIdx.x >> 1;
  const int sp   = blockIdx.x & 1;
  const int t    = threadIdx.x;
  const int lane = t & 63;
  const int w    = t >> 6;
  const bool producer = (w < 4);   // waves 0-3 stage docs; waves 4-7 compute

  const int dr = t >> 3;           // producer doc row 0..31 (threads 0..255)
  const int dj = t & 7;
  const int tokbase = b * ND + sp * DPB;

  // ---- producer staging routine: 256 threads, 8 per doc row, chunk=32 rows ----
  // Token comes from the phase-A prefetch; K-pad already zeroed in phase A.
  auto stage = [&](int td, int buf) {
    const float4* rowp = (const float4*)(emb + (size_t)td * NE);

    float4 v[10];                  // all loads issued before any use (MLP)
    #pragma unroll
    for (int i = 0; i < 9; ++i) v[i] = rowp[dj + 8 * i];
    v[9] = (dj < 3) ? rowp[dj + 72] : make_float4(0.f, 0.f, 0.f, 0.f);

    float ss = 0.0f;
    #pragma unroll
    for (int i = 0; i < 10; ++i) {
      ss += v[i].x * v[i].x + v[i].y * v[i].y + v[i].z * v[i].z + v[i].w * v[i].w;
      if (i < 9 || dj < 3) {
        bf16x4 h;
        h[0] = (__bf16)v[i].x; h[1] = (__bf16)v[i].y;
        h[2] = (__bf16)v[i].z; h[3] = (__bf16)v[i].w;
        *(bf16x4*)&dlds[buf][dr][4 * (dj + 8 * i)] = h;
      }
    }
    ss += __shfl_xor(ss, 1, 8);
    ss += __shfl_xor(ss, 2, 8);
    ss += __shfl_xor(ss, 4, 8);
    if (dj == 0) dscale[buf][dr] = (td > 0) ? 1.0f / (sqrtf(ss) + 1e-13f) : 0.0f;
  };

  // ---- phase A: producers prefetch tokens + stage chunk 0; consumers: query ----
  if (producer) {
    // one load+write per thread covers all 8 chunks x 32 rows of tokens
    tdlds[dj][dr] = dtok[tokbase + dj * CHUNK + dr];
    const int td0 = dtok[tokbase + dr];      // chunk-0 token (8-lane broadcast line)

    for (int i = t; i < QK_SZ; i += 256)     // zero qkl for k>=1
      if (i % NK) qkl[i] = 0.0f;

    // zero the K-pad [NE..320) of BOTH buffers once; stage() never touches it
    if (dj < 5) {
      bf16x4 z = {};
      *(bf16x4*)&dlds[0][dr][NE + 4 * dj] = z;
      *(bf16x4*)&dlds[1][dr][NE + 4 * dj] = z;
    }

    stage(td0, 0);
  } else {
    const int r = (t >> 3) & 31;   // query row 0..31 (8 threads per row)
    const int j = t & 7;
    const int tq = qtok[b * NQ + r];
    const float4* rowp = (const float4*)(emb + (size_t)tq * NE);

    float4 qv[10];
    #pragma unroll
    for (int i = 0; i < 9; ++i) qv[i] = rowp[j + 8 * i];
    qv[9] = (j < 3) ? rowp[j + 72] : make_float4(0.f, 0.f, 0.f, 0.f);

    float ss = 0.0f;
    #pragma unroll
    for (int i = 0; i < 10; ++i) {
      ss += qv[i].x * qv[i].x + qv[i].y * qv[i].y + qv[i].z * qv[i].z + qv[i].w * qv[i].w;
      if (i < 9 || j < 3) {
        bf16x4 h;
        h[0] = (__bf16)qv[i].x; h[1] = (__bf16)qv[i].y;
        h[2] = (__bf16)qv[i].z; h[3] = (__bf16)qv[i].w;
        *(bf16x4*)&qlds[r][4 * (j + 8 * i)] = h;
      }
    }
    if (j < 5) { bf16x4 z = {}; *(bf16x4*)&qlds[r][NE + 4 * j] = z; }  // K-pad
    ss += __shfl_xor(ss, 1, 8);
    ss += __shfl_xor(ss, 2, 8);
    ss += __shfl_xor(ss, 4, 8);
    if (j == 0) qscale[r] = (tq > 0) ? 1.0f / (sqrtf(ss) + 1e-13f) : 0.0f;

    // kernel 0: count of this block's DPB docs with identical (nonzero) token
    int cnt = 0;
    #pragma unroll 4
    for (int jj = 0; jj < 32; ++jj) {
      int td = dtok[b * ND + sp * DPB + j + 8 * jj];
      cnt += (tq > 0 && td == tq) ? 1 : 0;
    }
    cnt += __shfl_xor(cnt, 1, 8);
    cnt += __shfl_xor(cnt, 2, 8);
    cnt += __shfl_xor(cnt, 4, 8);
    if (j == 0) qkl[r * NK] = (float)cnt;
  }
  __syncthreads();   // qlds/qscale/qkl/tdlds + chunk 0 + pads ready

  // ---- consumer tile assignment: 4 waves cover 2 m-tiles x 2 n-tiles ----
  const int cw   = w - 4;          // consumer wave 0..3
  const int mt   = cw >> 1;        // q rows 16mt..16mt+15
  const int nt   = cw & 1;         // docs 16nt..16nt+15 within chunk
  const int l15  = lane & 15;
  const int quad = lane >> 4;

  const float muk[10] = {0.9f, 0.7f, 0.5f, 0.3f, 0.1f,
                         -0.1f, -0.3f, -0.5f, -0.7f, -0.9f};
  float rbfacc[4][10];
  #pragma unroll
  for (int r4 = 0; r4 < 4; ++r4)
    #pragma unroll
    for (int k = 0; k < 10; ++k) rbfacc[r4][k] = 0.0f;

  const __bf16* aptr = &qlds[((mt < 0 ? 0 : mt) * 16 + l15) & 31][quad * 8];

  // ---- main loop: producers stage ch+1 (token from LDS, payload issues at
  // window open) while consumers process ch ----
  #pragma unroll 1
  for (int ch = 0; ch < NCHUNK; ++ch) {
    if (producer) {
      if (ch + 1 < NCHUNK) stage(tdlds[ch + 1][dr], (ch + 1) & 1);
    } else {
      const int buf = ch & 1;
      const __bf16* bptr = &dlds[buf][nt * 16 + l15][quad * 8];

      f32x4 acc = {};
      #pragma unroll
      for (int kk = 0; kk < 10; ++kk) {
        bf16x8 av = *(const bf16x8*)(aptr + kk * 32);
        bf16x8 bv = *(const bf16x8*)(bptr + kk * 32);
        acc = __builtin_amdgcn_mfma_f32_16x16x32_bf16(av, bv, acc, 0, 0, 0);
      }

      // RBF accumulate (kernels 1..10). C layout: col(doc)=l15, row(q)=quad*4+reg.
      const float ds = dscale[buf][nt * 16 + l15];
      #pragma unroll
      for (int r4 = 0; r4 < 4; ++r4) {
        const float qs = qscale[mt * 16 + quad * 4 + r4];
        const float s = qs * ds;
        const float mm = (s == 0.0f) ? 1e8f : acc[r4] * s;  // masked -> rbf underflows to 0
        #pragma unroll
        for (int k = 0; k < 10; ++k) {
          float d = mm - muk[k];
          rbfacc[r4][k] += __builtin_amdgcn_exp2f(d * d * -72.13475204444817f);
        }
      }
    }
    __syncthreads();   // stage(ch+1) complete; consumers done reading buf ch&1
  }

  // ---- consumers: reduce rbfacc over the 16 doc-columns, add into qkl ----
  if (!producer) {
    #pragma unroll
    for (int r4 = 0; r4 < 4; ++r4)
      #pragma unroll
      for (int k = 0; k < 10; ++k) {
        float vv = rbfacc[r4][k];
        vv += __shfl_xor(vv, 1);
        vv += __shfl_xor(vv, 2);
        vv += __shfl_xor(vv, 4);
        vv += __shfl_xor(vv, 8);
        if (l15 == 0) atomicAdd(&qkl[(mt * 16 + quad * 4 + r4) * NK + k + 1], vv);
      }
  }
  __syncthreads();

  // ---- write this block's partial qk slice ----
  float* pp = partial + ((size_t)b * SPLITS + sp) * QK_SZ;
  for (int i = t; i < QK_SZ; i += NT) pp[i] = qkl[i];
}

__global__ __launch_bounds__(64) void knrm_epi(
    const float* __restrict__ partial,
    const float* __restrict__ fcw,
    const float* __restrict__ fcb,
    float* __restrict__ out)
{
  const int b = blockIdx.x;
  const int lane = threadIdx.x;
  const float* pb = partial + (size_t)b * SPLITS * QK_SZ;
  float acc = 0.0f;
  for (int i = lane; i < QK_SZ; i += 64) {
    float s = pb[i] + pb[i + QK_SZ];
    acc += logf(fmaxf(s, 1e-10f)) * 0.01f * fcw[i % NK];
  }
  #pragma unroll
  for (int off = 1; off < 64; off <<= 1) acc += __shfl_xor(acc, off);
  if (lane == 0) out[b] = acc + fcb[0];
}

extern "C" void kernel_launch(void* const* d_in, const int* in_sizes, int n_in,
                              void* d_out, int out_size, void* d_ws, size_t ws_size,
                              hipStream_t stream) {
  const int* qtok = (const int*)d_in[0];
  const int* dtok = (const int*)d_in[1];
  const float* emb = (const float*)d_in[2];
  const float* fcw = (const float*)d_in[3];
  const float* fcb = (const float*)d_in[4];
  float* out = (float*)d_out;
  float* partial = (float*)d_ws;   // NB*SPLITS*QK_SZ floats = 720 KB

  knrm_main<<<NB * SPLITS, NT, 0, stream>>>(qtok, dtok, emb, partial);
  knrm_epi<<<NB, 64, 0, stream>>>(partial, fcw, fcb, out);
}

// Round 4
// 190.921 us; speedup vs baseline: 1.3726x; 1.0051x over previous
//
#include <hip/hip_runtime.h>
#include <hip/hip_bf16.h>
#include <math.h>

// KNRM fused kernel for MI355X (gfx950) — round 12.
// B=256, Q=32, D=512, E=300, V=100k, K=11.
//
// R12 = R11 (best known, 191.9 us: producer/consumer wave specialization,
// double-buffered doc tiles, dtok LDS prefetch, hoisted K-pad zeroing)
// + XCD pair co-location: default dispatch maps consecutive blockIdx round-
// robin across the 8 XCDs, so the two sp-splits of batch b (which share the
// SAME 32 query embedding rows, 38.4 KB) land on different XCDs and fetch
// them twice from HBM. Remap blockIdx so both splits of b share one XCD and
// adjacent dispatch slots: the second q-fetch hits L2/in-flight, removing
// ~10 MB of duplicated fetch and correlating the pair's token-line reads.
// Bijection: u=blockIdx.x; xcd=u&7; s=u>>3; b=xcd*32+(s>>1); sp=s&1.
// R9/R10 post-mortem stands: no persistent cross-barrier register pipelines;
// barriers stay __syncthreads.
// Kernel 0 (sigma=1e-4) = exact-token-match counter via integer compare.

#define NB 256
#define NQ 32
#define ND 512
#define NE 300
#define LROW 328    // LDS row stride in bf16 (656 B = 16B-aligned, 4-bank row skew)
#define SPLITS 2
#define DPB 256     // docs per block
#define CHUNK 32
#define NCHUNK 8
#define NT 512
#define NK 11
#define QK_SZ (NQ * NK)   // 352

typedef __bf16 bf16x8 __attribute__((ext_vector_type(8)));
typedef __bf16 bf16x4 __attribute__((ext_vector_type(4)));
typedef float f32x4 __attribute__((ext_vector_type(4)));

__global__ __launch_bounds__(NT, 4) void knrm_main(
    const int* __restrict__ qtok,
    const int* __restrict__ dtok,
    const float* __restrict__ emb,
    float* __restrict__ partial)   // [NB][SPLITS][QK_SZ]
{
  __shared__ __align__(16) __bf16 qlds[NQ][LROW];          // 20992 B
  __shared__ __align__(16) __bf16 dlds[2][CHUNK][LROW];    // 41984 B
  __shared__ float qscale[NQ];
  __shared__ float dscale[2][CHUNK];
  __shared__ float qkl[QK_SZ];
  __shared__ int tdlds[NCHUNK][CHUNK];                     // 1024 B token prefetch

  // XCD pair co-location: both sp-splits of batch b on the same XCD,
  // adjacent dispatch slots. (If the HW mapping differs this is a harmless
  // bijective permutation.)
  const int u    = blockIdx.x;
  const int xcd  = u & 7;
  const int s    = u >> 3;         // 0..63
  const int b    = xcd * 32 + (s >> 1);
  const int sp   = s & 1;
  const int t    = threadIdx.x;
  const int lane = t & 63;
  const int w    = t >> 6;
  const bool producer = (w < 4);   // waves 0-3 stage docs; waves 4-7 compute

  const int dr = t >> 3;           // producer doc row 0..31 (threads 0..255)
  const int dj = t & 7;
  const int tokbase = b * ND + sp * DPB;

  // ---- producer staging routine: 256 threads, 8 per doc row, chunk=32 rows ----
  // Token comes from the phase-A prefetch; K-pad already zeroed in phase A.
  auto stage = [&](int td, int buf) {
    const float4* rowp = (const float4*)(emb + (size_t)td * NE);

    float4 v[10];                  // all loads issued before any use (MLP)
    #pragma unroll
    for (int i = 0; i < 9; ++i) v[i] = rowp[dj + 8 * i];
    v[9] = (dj < 3) ? rowp[dj + 72] : make_float4(0.f, 0.f, 0.f, 0.f);

    float ss = 0.0f;
    #pragma unroll
    for (int i = 0; i < 10; ++i) {
      ss += v[i].x * v[i].x + v[i].y * v[i].y + v[i].z * v[i].z + v[i].w * v[i].w;
      if (i < 9 || dj < 3) {
        bf16x4 h;
        h[0] = (__bf16)v[i].x; h[1] = (__bf16)v[i].y;
        h[2] = (__bf16)v[i].z; h[3] = (__bf16)v[i].w;
        *(bf16x4*)&dlds[buf][dr][4 * (dj + 8 * i)] = h;
      }
    }
    ss += __shfl_xor(ss, 1, 8);
    ss += __shfl_xor(ss, 2, 8);
    ss += __shfl_xor(ss, 4, 8);
    if (dj == 0) dscale[buf][dr] = (td > 0) ? 1.0f / (sqrtf(ss) + 1e-13f) : 0.0f;
  };

  // ---- phase A: producers prefetch tokens + stage chunk 0; consumers: query ----
  if (producer) {
    // one load+write per thread covers all 8 chunks x 32 rows of tokens
    tdlds[dj][dr] = dtok[tokbase + dj * CHUNK + dr];
    const int td0 = dtok[tokbase + dr];      // chunk-0 token (8-lane broadcast line)

    for (int i = t; i < QK_SZ; i += 256)     // zero qkl for k>=1
      if (i % NK) qkl[i] = 0.0f;

    // zero the K-pad [NE..320) of BOTH buffers once; stage() never touches it
    if (dj < 5) {
      bf16x4 z = {};
      *(bf16x4*)&dlds[0][dr][NE + 4 * dj] = z;
      *(bf16x4*)&dlds[1][dr][NE + 4 * dj] = z;
    }

    stage(td0, 0);
  } else {
    const int r = (t >> 3) & 31;   // query row 0..31 (8 threads per row)
    const int j = t & 7;
    const int tq = qtok[b * NQ + r];
    const float4* rowp = (const float4*)(emb + (size_t)tq * NE);

    float4 qv[10];
    #pragma unroll
    for (int i = 0; i < 9; ++i) qv[i] = rowp[j + 8 * i];
    qv[9] = (j < 3) ? rowp[j + 72] : make_float4(0.f, 0.f, 0.f, 0.f);

    float ss = 0.0f;
    #pragma unroll
    for (int i = 0; i < 10; ++i) {
      ss += qv[i].x * qv[i].x + qv[i].y * qv[i].y + qv[i].z * qv[i].z + qv[i].w * qv[i].w;
      if (i < 9 || j < 3) {
        bf16x4 h;
        h[0] = (__bf16)qv[i].x; h[1] = (__bf16)qv[i].y;
        h[2] = (__bf16)qv[i].z; h[3] = (__bf16)qv[i].w;
        *(bf16x4*)&qlds[r][4 * (j + 8 * i)] = h;
      }
    }
    if (j < 5) { bf16x4 z = {}; *(bf16x4*)&qlds[r][NE + 4 * j] = z; }  // K-pad
    ss += __shfl_xor(ss, 1, 8);
    ss += __shfl_xor(ss, 2, 8);
    ss += __shfl_xor(ss, 4, 8);
    if (j == 0) qscale[r] = (tq > 0) ? 1.0f / (sqrtf(ss) + 1e-13f) : 0.0f;

    // kernel 0: count of this block's DPB docs with identical (nonzero) token
    int cnt = 0;
    #pragma unroll 4
    for (int jj = 0; jj < 32; ++jj) {
      int td = dtok[b * ND + sp * DPB + j + 8 * jj];
      cnt += (tq > 0 && td == tq) ? 1 : 0;
    }
    cnt += __shfl_xor(cnt, 1, 8);
    cnt += __shfl_xor(cnt, 2, 8);
    cnt += __shfl_xor(cnt, 4, 8);
    if (j == 0) qkl[r * NK] = (float)cnt;
  }
  __syncthreads();   // qlds/qscale/qkl/tdlds + chunk 0 + pads ready

  // ---- consumer tile assignment: 4 waves cover 2 m-tiles x 2 n-tiles ----
  const int cw   = w - 4;          // consumer wave 0..3
  const int mt   = cw >> 1;        // q rows 16mt..16mt+15
  const int nt   = cw & 1;         // docs 16nt..16nt+15 within chunk
  const int l15  = lane & 15;
  const int quad = lane >> 4;

  const float muk[10] = {0.9f, 0.7f, 0.5f, 0.3f, 0.1f,
                         -0.1f, -0.3f, -0.5f, -0.7f, -0.9f};
  float rbfacc[4][10];
  #pragma unroll
  for (int r4 = 0; r4 < 4; ++r4)
    #pragma unroll
    for (int k = 0; k < 10; ++k) rbfacc[r4][k] = 0.0f;

  const __bf16* aptr = &qlds[((mt < 0 ? 0 : mt) * 16 + l15) & 31][quad * 8];

  // ---- main loop: producers stage ch+1 (token from LDS, payload issues at
  // window open) while consumers process ch ----
  #pragma unroll 1
  for (int ch = 0; ch < NCHUNK; ++ch) {
    if (producer) {
      if (ch + 1 < NCHUNK) stage(tdlds[ch + 1][dr], (ch + 1) & 1);
    } else {
      const int buf = ch & 1;
      const __bf16* bptr = &dlds[buf][nt * 16 + l15][quad * 8];

      f32x4 acc = {};
      #pragma unroll
      for (int kk = 0; kk < 10; ++kk) {
        bf16x8 av = *(const bf16x8*)(aptr + kk * 32);
        bf16x8 bv = *(const bf16x8*)(bptr + kk * 32);
        acc = __builtin_amdgcn_mfma_f32_16x16x32_bf16(av, bv, acc, 0, 0, 0);
      }

      // RBF accumulate (kernels 1..10). C layout: col(doc)=l15, row(q)=quad*4+reg.
      const float ds = dscale[buf][nt * 16 + l15];
      #pragma unroll
      for (int r4 = 0; r4 < 4; ++r4) {
        const float qs = qscale[mt * 16 + quad * 4 + r4];
        const float s2 = qs * ds;
        const float mm = (s2 == 0.0f) ? 1e8f : acc[r4] * s2;  // masked -> rbf underflows to 0
        #pragma unroll
        for (int k = 0; k < 10; ++k) {
          float d = mm - muk[k];
          rbfacc[r4][k] += __builtin_amdgcn_exp2f(d * d * -72.13475204444817f);
        }
      }
    }
    __syncthreads();   // stage(ch+1) complete; consumers done reading buf ch&1
  }

  // ---- consumers: reduce rbfacc over the 16 doc-columns, add into qkl ----
  if (!producer) {
    #pragma unroll
    for (int r4 = 0; r4 < 4; ++r4)
      #pragma unroll
      for (int k = 0; k < 10; ++k) {
        float vv = rbfacc[r4][k];
        vv += __shfl_xor(vv, 1);
        vv += __shfl_xor(vv, 2);
        vv += __shfl_xor(vv, 4);
        vv += __shfl_xor(vv, 8);
        if (l15 == 0) atomicAdd(&qkl[(mt * 16 + quad * 4 + r4) * NK + k + 1], vv);
      }
  }
  __syncthreads();

  // ---- write this block's partial qk slice ----
  float* pp = partial + ((size_t)b * SPLITS + sp) * QK_SZ;
  for (int i = t; i < QK_SZ; i += NT) pp[i] = qkl[i];
}

__global__ __launch_bounds__(64) void knrm_epi(
    const float* __restrict__ partial,
    const float* __restrict__ fcw,
    const float* __restrict__ fcb,
    float* __restrict__ out)
{
  const int b = blockIdx.x;
  const int lane = threadIdx.x;
  const float* pb = partial + (size_t)b * SPLITS * QK_SZ;
  float acc = 0.0f;
  for (int i = lane; i < QK_SZ; i += 64) {
    float s = pb[i] + pb[i + QK_SZ];
    acc += logf(fmaxf(s, 1e-10f)) * 0.01f * fcw[i % NK];
  }
  #pragma unroll
  for (int off = 1; off < 64; off <<= 1) acc += __shfl_xor(acc, off);
  if (lane == 0) out[b] = acc + fcb[0];
}

extern "C" void kernel_launch(void* const* d_in, const int* in_sizes, int n_in,
                              void* d_out, int out_size, void* d_ws, size_t ws_size,
                              hipStream_t stream) {
  const int* qtok = (const int*)d_in[0];
  const int* dtok = (const int*)d_in[1];
  const float* emb = (const float*)d_in[2];
  const float* fcw = (const float*)d_in[3];
  const float* fcb = (const float*)d_in[4];
  float* out = (float*)d_out;
  float* partial = (float*)d_ws;   // NB*SPLITS*QK_SZ floats = 720 KB

  knrm_main<<<NB * SPLITS, NT, 0, stream>>>(qtok, dtok, emb, partial);
  knrm_epi<<<NB, 64, 0, stream>>>(partial, fcw, fcb, out);
}